// Round 1
// 191.796 us; speedup vs baseline: 1.0399x; 1.0399x over previous
//
#include <hip/hip_runtime.h>

// SSIM loss, fused. R6: software-pipelined single-barrier-per-row version of
// R5's proven conflict-free layout.
//  - Same algebra as R5: 4 channels u=x+y, v=x-y -> Su,Sv,Suu,Svv.
//  - Same two-level horizontal sums: S (column sums) + Q (aligned quad sums),
//    any 11-tap window = 3 S-reads + 2 Q-reads, all lane-stride-1 / broadcast
//    (R2-proven 0.0 LDS bank conflicts).
//  - NEW: CHUNK=1 with DOUBLE-BUFFERED S/Q (same 21.1 KB LDS total) and a
//    register prefetch pipeline. Per output row:
//       hphase(buf p) -> consume prefetched rows (vmcnt wait) -> issue next
//       row's global loads -> write S/Q into buf !p -> ONE __syncthreads().
//    Global-load latency now hides under writeSQ + barrier + next hphase
//    instead of sitting exposed between the two barriers of the old chunk
//    loop (counters showed HBM 21%, VALU 21%, occupancy 23% => latency-bound).
// Arithmetic order identical to R5 => bit-identical result.

#define IMG_H 512
#define IMG_W 512
#define N_IMG 64
#define STRIP 16           // output rows per block -> grid (32,64)=2048 blocks
#define NTHREADS 128
#define SSZ 528            // S: idx = col + 8, cols -8..519 (pads zero)
#define QSZ 132            // Q: idx = m + 2,  m = -2..129  (pads zero)
#define ROWSZ (SSZ + QSZ)  // 660 floats per [buf][ch] (mult of 4 -> 16B align)

__global__ __launch_bounds__(NTHREADS) void ssim_kernel(const float* __restrict__ img1,
                                                        const float* __restrict__ img2,
                                                        float* __restrict__ ws) {
    __shared__ __align__(16) float V[2][4][ROWSZ];  // double buffer; ch: u,v,uu,vv
    __shared__ float wsum[2];
    const int t = threadIdx.x;
    const int b = blockIdx.y;
    const int r0 = blockIdx.x * STRIP;
    const float* __restrict__ p1 = img1 + (size_t)b * (IMG_H * IMG_W);
    const float* __restrict__ p2 = img2 + (size_t)b * (IMG_H * IMG_W);

    // Zero all of V once; pad regions are never written after this.
    for (int i = t; i < 2 * 4 * ROWSZ; i += NTHREADS) (&V[0][0][0])[i] = 0.0f;

    // --- V phase: thread owns 4 adjacent cols c4..c4+3 (float4 loads) ---
    const int c4 = 4 * t;
    float cs[4][4];
#pragma unroll
    for (int ch = 0; ch < 4; ++ch)
#pragma unroll
        for (int j = 0; j < 4; ++j) cs[ch][j] = 0.0f;

    auto addrow = [&](int r) {
        float4 x = *(const float4*)(p1 + (size_t)r * IMG_W + c4);
        float4 y = *(const float4*)(p2 + (size_t)r * IMG_W + c4);
        float xs[4] = {x.x, x.y, x.z, x.w}, ys[4] = {y.x, y.y, y.z, y.w};
#pragma unroll
        for (int j = 0; j < 4; ++j) {
            float u = xs[j] + ys[j], v = xs[j] - ys[j];
            cs[0][j] += u;                  cs[1][j] += v;
            cs[2][j] = fmaf(u, u, cs[2][j]); cs[3][j] = fmaf(v, v, cs[3][j]);
        }
    };

    // Prefetch registers: rows needed to advance the vertical window to the
    // NEXT output row (add row rn+5, subtract row rn-6).
    float4 pax, pay, psx, psy;
    auto prefetch = [&](int rn) {
        if (rn >= r0 + STRIP) return;          // past last output row
        const int ra = rn + 5, rs = rn - 6;
        if (ra < IMG_H) {
            pax = *(const float4*)(p1 + (size_t)ra * IMG_W + c4);
            pay = *(const float4*)(p2 + (size_t)ra * IMG_W + c4);
        }
        if (rs >= 0) {
            psx = *(const float4*)(p1 + (size_t)rs * IMG_W + c4);
            psy = *(const float4*)(p2 + (size_t)rs * IMG_W + c4);
        }
    };
    auto consume = [&](int rn) {
        const int ra = rn + 5, rs = rn - 6;
        if (ra < IMG_H) {
            float xs[4] = {pax.x, pax.y, pax.z, pax.w};
            float ys[4] = {pay.x, pay.y, pay.z, pay.w};
#pragma unroll
            for (int j = 0; j < 4; ++j) {
                float u = xs[j] + ys[j], v = xs[j] - ys[j];
                cs[0][j] += u;                  cs[1][j] += v;
                cs[2][j] = fmaf(u, u, cs[2][j]); cs[3][j] = fmaf(v, v, cs[3][j]);
            }
        }
        if (rs >= 0) {
            float xs[4] = {psx.x, psx.y, psx.z, psx.w};
            float ys[4] = {psy.x, psy.y, psy.z, psy.w};
#pragma unroll
            for (int j = 0; j < 4; ++j) {
                float u = xs[j] + ys[j], v = xs[j] - ys[j];
                cs[0][j] -= u;                  cs[1][j] -= v;
                cs[2][j] = fmaf(-u, u, cs[2][j]); cs[3][j] = fmaf(-v, v, cs[3][j]);
            }
        }
    };
    auto writeSQ = [&](int p) {
#pragma unroll
        for (int ch = 0; ch < 4; ++ch) {
            *(float4*)&V[p][ch][8 + c4] =
                make_float4(cs[ch][0], cs[ch][1], cs[ch][2], cs[ch][3]);
            V[p][ch][SSZ + 2 + t] = (cs[ch][0] + cs[ch][1]) + (cs[ch][2] + cs[ch][3]);
        }
    };

    // --- H phase offsets: px cols t+128k share residue rho = t&3 ---
    int offS[4][3], offQ[4][2];
#pragma unroll
    for (int k = 0; k < 4; ++k) {
        const int c = t + 128 * k;
        const int rho = c & 3;
        int e0, e1, e2;
        if (rho == 0)      { e0 = -5; e1 =  4; e2 =  5; }
        else if (rho == 1) { e0 =  3; e1 =  4; e2 =  5; }
        else if (rho == 2) { e0 = -5; e1 = -4; e2 = -3; }
        else               { e0 = -5; e1 = -4; e2 =  5; }
        offS[k][0] = c + 8 + e0; offS[k][1] = c + 8 + e1; offS[k][2] = c + 8 + e2;
        const int mlo = (c >> 2) + ((rho < 2) ? -1 : 0);
        offQ[k][0] = SSZ + 2 + mlo; offQ[k][1] = SSZ + 3 + mlo;
    }

    // Warm vertical window for output row r0 (zero pad outside image).
    {
        int rlo = r0 - 5; if (rlo < 0) rlo = 0;
        const int rhi = r0 + 5;              // r0 <= 496 -> rhi <= 501 < 512
        for (int r = rlo; r <= rhi; ++r) addrow(r);
    }
    __syncthreads();          // LDS zeroing complete
    writeSQ(0);               // S/Q for row r0 into buf 0
    prefetch(r0 + 1);         // loads for row r0+1 in flight across barrier
    __syncthreads();          // buf 0 visible

    constexpr float inv  = 1.0f / 121.0f;
    constexpr float inv2 = 0.5f / 121.0f;
    constexpr float C1c = 0.01f * 0.01f;
    constexpr float C2c = 0.03f * 0.03f;
    float acc = 0.0f;

    auto hphase = [&](int p) {
        const float* __restrict__ Vf = &V[p][0][0];
#pragma unroll
        for (int k = 0; k < 4; ++k) {
            float W[4];
#pragma unroll
            for (int ch = 0; ch < 4; ++ch) {
                const int base = ch * ROWSZ;
                W[ch] = ((Vf[base + offS[k][0]] + Vf[base + offS[k][1]]) +
                         (Vf[base + offS[k][2]] + Vf[base + offQ[k][0]])) +
                        Vf[base + offQ[k][1]];
            }
            float mu_u = W[0] * inv, mu_v = W[1] * inv;
            float uu = mu_u * mu_u, vv = mu_v * mu_v;
            float P = 0.5f * (uu + vv);      // mu1^2 + mu2^2
            float M = 0.5f * (uu - vv);      // 2*mu1*mu2
            float A = fmaf(W[2] + W[3], inv2, -P);  // sig1^2 + sig2^2
            float B = fmaf(W[2] - W[3], inv2, -M);  // 2*sig12
            float num = (M + C1c) * (B + C2c);
            float den = (P + C1c) * (A + C2c);
            acc += __fdividef(num, den);
        }
    };

    // Main pipeline: one barrier per output row.
    //  hphase reads buf p (row r); writes for row r+1 go to buf !p (no WAR);
    //  writes to buf p for row r+2 happen only after the next barrier.
    for (int i = 0; i < STRIP - 1; ++i) {
        hphase(i & 1);            // SSIM for row r0+i
        consume(r0 + i + 1);      // vmcnt wait: loads issued one iter ago
        prefetch(r0 + i + 2);     // issue next loads ASAP (in flight > 1 row)
        writeSQ((i + 1) & 1);     // S/Q for row r0+i+1
        __syncthreads();
    }
    hphase((STRIP - 1) & 1);      // last row

    // Reduce: wave shuffle -> LDS -> one atomic per block.
#pragma unroll
    for (int off = 32; off > 0; off >>= 1) acc += __shfl_down(acc, off);
    if ((t & 63) == 0) wsum[t >> 6] = acc;
    __syncthreads();
    if (t == 0) atomicAdd(ws, wsum[0] + wsum[1]);
}

__global__ void ssim_finalize(const float* __restrict__ ws, float* __restrict__ out) {
    constexpr float inv_n = 1.0f / (float)((size_t)N_IMG * IMG_H * IMG_W);
    out[0] = 1.0f - ws[0] * inv_n;
}

extern "C" void kernel_launch(void* const* d_in, const int* in_sizes, int n_in,
                              void* d_out, int out_size, void* d_ws, size_t ws_size,
                              hipStream_t stream) {
    const float* img1 = (const float*)d_in[0];
    const float* img2 = (const float*)d_in[1];
    float* out = (float*)d_out;
    float* ws = (float*)d_ws;

    hipMemsetAsync(ws, 0, sizeof(float), stream);

    dim3 grid(IMG_H / STRIP, N_IMG);   // (32, 64) = 2048 blocks
    ssim_kernel<<<grid, NTHREADS, 0, stream>>>(img1, img2, ws);
    ssim_finalize<<<1, 1, 0, stream>>>(ws, out);
}